// Round 11
// baseline (791.925 us; speedup 1.0000x reference)
//
#include <hip/hip_runtime.h>
#include <math.h>

#define N_NODES 250000
#define N_EDGES 2500000
#define N_GRAPHS 512
#define BN_EPS 1e-5f
#define NT 500000   // 2*N_NODES offset slots (F then B)
#define INV_N (1.0f / (float)N_NODES)
#define NBUCK 245   // ceil(N_NODES / 1024)
#define BSHIFT 10

// bf16 helpers (RNE); bf16->fp32 is an exact bit shift.
__device__ __forceinline__ unsigned short f2bf(float x) {
    unsigned int u = __float_as_uint(x);
    unsigned int r = (u + 0x7FFFu + ((u >> 16) & 1u)) >> 16;
    return (unsigned short)r;
}
__device__ __forceinline__ float bf2f(unsigned short b) {
    return __uint_as_float(((unsigned int)b) << 16);
}

// ============== CSR build v3: two-level LDS bucket sort (R5 win) ============

__global__ __launch_bounds__(256)
void k_histA(const int* __restrict__ src, const int* __restrict__ dst,
             int* __restrict__ gcnt, int E)
{
    __shared__ int hF[256], hB[256];
    int t = threadIdx.x;
    hF[t] = 0; hB[t] = 0;
    __syncthreads();
    for (int e = blockIdx.x * 256 + t; e < E; e += gridDim.x * 256) {
        atomicAdd(&hF[dst[e] >> BSHIFT], 1);
        atomicAdd(&hB[src[e] >> BSHIFT], 1);
    }
    __syncthreads();
    if (hF[t]) atomicAdd(&gcnt[t], hF[t]);
    if (hB[t]) atomicAdd(&gcnt[256 + t], hB[t]);
}

__global__ void k_scanBk(const int* __restrict__ gcnt,
                         int* __restrict__ bOffF, int* __restrict__ bOffB,
                         int* __restrict__ cursF, int* __restrict__ cursB,
                         int* __restrict__ off)
{
    __shared__ int s[512];
    int t = threadIdx.x;   // 256
    int vF = (t < NBUCK) ? gcnt[t] : 0;
    int vB = (t < NBUCK) ? gcnt[256 + t] : 0;
    s[t] = vF; s[256 + t] = vB;
    __syncthreads();
    for (int o = 1; o < 256; o <<= 1) {
        int xF = (t >= o) ? s[t - o] : 0;
        int xB = (t >= o) ? s[256 + t - o] : 0;
        __syncthreads();
        s[t] += xF; s[256 + t] += xB;
        __syncthreads();
    }
    int exF = s[t] - vF;
    int exB = s[256 + t] - vB;
    if (t < NBUCK) {
        bOffF[t] = exF; cursF[t] = exF;
        bOffB[t] = exB; cursB[t] = exB;
    }
    if (t == 0) {
        bOffF[NBUCK] = N_EDGES;
        bOffB[NBUCK] = N_EDGES;
        off[NT] = 2 * N_EDGES;
    }
}

__global__ __launch_bounds__(256)
void k_scatA(const int* __restrict__ src, const int* __restrict__ dst,
             int* __restrict__ cursF, int* __restrict__ cursB,
             unsigned int* __restrict__ payF, unsigned int* __restrict__ payB, int E)
{
    __shared__ int hF[256], hB[256];
    __shared__ int cF[256], cB[256];
    int t = threadIdx.x;
    hF[t] = 0; hB[t] = 0;
    __syncthreads();
    int e0 = blockIdx.x * 256 + t, STR = gridDim.x * 256;
    for (int e = e0; e < E; e += STR) {
        atomicAdd(&hF[dst[e] >> BSHIFT], 1);
        atomicAdd(&hB[src[e] >> BSHIFT], 1);
    }
    __syncthreads();
    int baseF = 0, baseB = 0;
    if (t < NBUCK) {
        if (hF[t]) baseF = atomicAdd(&cursF[t], hF[t]);
        if (hB[t]) baseB = atomicAdd(&cursB[t], hB[t]);
    }
    __syncthreads();
    cF[t] = baseF; cB[t] = baseB;
    __syncthreads();
    for (int e = e0; e < E; e += STR) {
        int s = src[e], d = dst[e];
        int tf = atomicAdd(&cF[d >> BSHIFT], 1);
        payF[tf] = ((unsigned int)(d & 1023) << 18) | (unsigned int)s;
        int tb = atomicAdd(&cB[s >> BSHIFT], 1);
        payB[tb] = ((unsigned int)(s & 1023) << 18) | (unsigned int)d;
    }
}

__global__ __launch_bounds__(256)
void k_bucket(const unsigned int* __restrict__ payF, const unsigned int* __restrict__ payB,
              const int* __restrict__ bOffF, const int* __restrict__ bOffB,
              int* __restrict__ eidx, int* __restrict__ off)
{
    __shared__ int cnt[1024];
    __shared__ int ps[256];
    int blk = blockIdx.x;
    int d  = (blk >= NBUCK) ? 1 : 0;
    int bb = blk - d * NBUCK;
    const unsigned int* pay = d ? payB : payF;
    const int* bOff = d ? bOffB : bOffF;
    int t = threadIdx.x;
    int lo = bOff[bb], hi = bOff[bb + 1];

    #pragma unroll
    for (int k = 0; k < 4; k++) cnt[t + 256 * k] = 0;
    __syncthreads();
    for (int e = lo + t; e < hi; e += 256)
        atomicAdd(&cnt[pay[e] >> 18], 1);
    __syncthreads();

    int b4 = 4 * t;
    int v0 = cnt[b4], v1 = cnt[b4 + 1], v2 = cnt[b4 + 2], v3 = cnt[b4 + 3];
    int tsum = v0 + v1 + v2 + v3;
    ps[t] = tsum;
    __syncthreads();
    for (int o = 1; o < 256; o <<= 1) {
        int x = (t >= o) ? ps[t - o] : 0;
        __syncthreads();
        ps[t] += x;
        __syncthreads();
    }
    int run = ps[t] - tsum;
    int l0 = run, l1 = run + v0, l2 = run + v0 + v1, l3 = run + v0 + v1 + v2;
    cnt[b4] = l0; cnt[b4 + 1] = l1; cnt[b4 + 2] = l2; cnt[b4 + 3] = l3;

    int gbase = d * N_EDGES + lo;
    int node0 = bb * 1024 + b4;
    if (node0 + 0 < N_NODES) off[d * N_NODES + node0 + 0] = gbase + l0;
    if (node0 + 1 < N_NODES) off[d * N_NODES + node0 + 1] = gbase + l1;
    if (node0 + 2 < N_NODES) off[d * N_NODES + node0 + 2] = gbase + l2;
    if (node0 + 3 < N_NODES) off[d * N_NODES + node0 + 3] = gbase + l3;
    __syncthreads();

    for (int e = lo + t; e < hi; e += 256) {
        unsigned int p = pay[e];
        int r = atomicAdd(&cnt[p >> 18], 1);
        eidx[gbase + r] = (int)(p & 0x3FFFFu);
    }
}

// ================= pad x (N x 6 fp32) -> xpad (N x 8 fp32) ==================

__global__ void pad_x(const float* __restrict__ x, float* __restrict__ xpad, int n)
{
    int i = blockIdx.x * blockDim.x + threadIdx.x;   // one float2 out per thread
    if (i >= n * 4) return;
    int node = i >> 2, p2 = i & 3;
    float2 v;
    v.x = (2 * p2     < 6) ? x[node * 6 + 2 * p2]     : 0.f;
    v.y = (2 * p2 + 1 < 6) ? x[node * 6 + 2 * p2 + 1] : 0.f;
    *(float2*)(xpad + node * 8 + 2 * p2) = v;
}

// ============ layer-1 gather, PACKED: 4 lanes x float2 per padded row =======

__global__ __launch_bounds__(256, 8)
void gather6p(const float* __restrict__ xpad, const int* __restrict__ off,
              const int* __restrict__ eidx, float* __restrict__ agg, int ngroups)
{
    int tid = threadIdx.x;
    int p2   = tid & 3;       // float2 index within row (cols 2p2, 2p2+1)
    int slot = tid >> 2;      // 0..63 node slots per block
    for (int grp = blockIdx.x; grp < ngroups; grp += gridDim.x) {
        int node = grp * 64 + slot;
        bool nvalid = (node < N_NODES);
        int nd = nvalid ? node : 0;
        #pragma unroll
        for (int dir = 0; dir < 2; dir++) {
            int u = dir * N_NODES + nd;
            int k0 = off[u], k1 = off[u + 1];
            if (!nvalid) k1 = k0;
            float a0=0.f,a1=0.f,b0=0.f,b1=0.f,c0=0.f,c1=0.f,d0=0.f,d1=0.f;
            for (int p = k0; p < k1; p += 8) {
                #pragma unroll
                for (int q = 0; q < 8; q++) {
                    int kk = p + q;
                    bool act = (kk < k1);
                    int j = eidx[act ? kk : k0];
                    float2 v = *(const float2*)(xpad + j * 8 + 2 * p2);
                    float lo = act ? v.x : 0.f;
                    float hi = act ? v.y : 0.f;
                    if ((q & 3) == 0)      { a0 += lo; a1 += hi; }
                    else if ((q & 3) == 1) { b0 += lo; b1 += hi; }
                    else if ((q & 3) == 2) { c0 += lo; c1 += hi; }
                    else                   { d0 += lo; d1 += hi; }
                }
            }
            if (nvalid && p2 < 3) {
                float2 s;
                s.x = (a0 + b0) + (c0 + d0);
                s.y = (a1 + b1) + (c1 + d1);
                *(float2*)(agg + nd * 12 + dir * 6 + 2 * p2) = s;
            }
        }
    }
}

// ====== bf16 gather, uint2: 8 lanes/row x 8B, 8-deep queue (A of A/B) =======
// R10: gather16 (16 lanes x 4B) was ~60% VALUBusy -> instruction-bound.
// Halve load/convert instruction count per byte. 16 accums, (256,8).

__global__ __launch_bounds__(256, 8)
void gather8x2(const unsigned short* __restrict__ xb, const int* __restrict__ off,
               const int* __restrict__ eidx, float* __restrict__ agg, int ngroups)
{
    const uint2* xu = (const uint2*)xb;   // row = 8 uint2
    int tid = threadIdx.x;
    int fp = tid & 7;        // uint2 index within row (features 4fp..4fp+3)
    int gg = tid >> 3;       // 32 node slots per block
    for (int grp = blockIdx.x; grp < ngroups; grp += gridDim.x) {
        int node = grp * 32 + gg;
        bool nvalid = (node < N_NODES);
        int nd = nvalid ? node : 0;
        #pragma unroll
        for (int dir = 0; dir < 2; dir++) {
            int u = dir * N_NODES + nd;
            int k0 = off[u], k1 = off[u + 1];
            if (!nvalid) k1 = k0;
            float sA[4] = {0.f,0.f,0.f,0.f};
            float sB[4] = {0.f,0.f,0.f,0.f};
            float sC[4] = {0.f,0.f,0.f,0.f};
            float sD[4] = {0.f,0.f,0.f,0.f};
            for (int p = k0; p < k1; p += 8) {
                #pragma unroll
                for (int q = 0; q < 8; q++) {
                    int kk = p + q;
                    bool act = (kk < k1);
                    int j = eidx[act ? kk : k0];
                    uint2 v = xu[j * 8 + fp];
                    float f0 = act ? __uint_as_float(v.x << 16) : 0.f;
                    float f1 = act ? __uint_as_float(v.x & 0xFFFF0000u) : 0.f;
                    float f2 = act ? __uint_as_float(v.y << 16) : 0.f;
                    float f3 = act ? __uint_as_float(v.y & 0xFFFF0000u) : 0.f;
                    if ((q & 3) == 0)      { sA[0]+=f0; sA[1]+=f1; sA[2]+=f2; sA[3]+=f3; }
                    else if ((q & 3) == 1) { sB[0]+=f0; sB[1]+=f1; sB[2]+=f2; sB[3]+=f3; }
                    else if ((q & 3) == 2) { sC[0]+=f0; sC[1]+=f1; sC[2]+=f2; sC[3]+=f3; }
                    else                   { sD[0]+=f0; sD[1]+=f1; sD[2]+=f2; sD[3]+=f3; }
                }
            }
            if (nvalid) {
                float4 s;
                s.x = (sA[0] + sB[0]) + (sC[0] + sD[0]);
                s.y = (sA[1] + sB[1]) + (sC[1] + sD[1]);
                s.z = (sA[2] + sB[2]) + (sC[2] + sD[2]);
                s.w = (sA[3] + sB[3]) + (sC[3] + sD[3]);
                *(float4*)(agg + nd * 64 + dir * 32 + 4 * fp) = s;
            }
        }
    }
}

// ====== bf16 gather, uint4: 4 lanes/row x 16B, 4-deep queue (B of A/B) ======
// Quarter the instruction count per byte; 32 accums -> (256,6) 85-VGPR budget.

__global__ __launch_bounds__(256, 6)
void gather4x4(const unsigned short* __restrict__ xb, const int* __restrict__ off,
               const int* __restrict__ eidx, float* __restrict__ agg, int ngroups)
{
    const uint4* xu = (const uint4*)xb;   // row = 4 uint4
    int tid = threadIdx.x;
    int fp = tid & 3;        // uint4 index within row (features 8fp..8fp+7)
    int gg = tid >> 2;       // 64 node slots per block
    for (int grp = blockIdx.x; grp < ngroups; grp += gridDim.x) {
        int node = grp * 64 + gg;
        bool nvalid = (node < N_NODES);
        int nd = nvalid ? node : 0;
        #pragma unroll
        for (int dir = 0; dir < 2; dir++) {
            int u = dir * N_NODES + nd;
            int k0 = off[u], k1 = off[u + 1];
            if (!nvalid) k1 = k0;
            float sA[8] = {0.f,0.f,0.f,0.f,0.f,0.f,0.f,0.f};
            float sB[8] = {0.f,0.f,0.f,0.f,0.f,0.f,0.f,0.f};
            float sC[8] = {0.f,0.f,0.f,0.f,0.f,0.f,0.f,0.f};
            float sD[8] = {0.f,0.f,0.f,0.f,0.f,0.f,0.f,0.f};
            for (int p = k0; p < k1; p += 4) {
                #pragma unroll
                for (int q = 0; q < 4; q++) {
                    int kk = p + q;
                    bool act = (kk < k1);
                    int j = eidx[act ? kk : k0];
                    uint4 v = xu[j * 4 + fp];
                    float f0 = act ? __uint_as_float(v.x << 16) : 0.f;
                    float f1 = act ? __uint_as_float(v.x & 0xFFFF0000u) : 0.f;
                    float f2 = act ? __uint_as_float(v.y << 16) : 0.f;
                    float f3 = act ? __uint_as_float(v.y & 0xFFFF0000u) : 0.f;
                    float f4 = act ? __uint_as_float(v.z << 16) : 0.f;
                    float f5 = act ? __uint_as_float(v.z & 0xFFFF0000u) : 0.f;
                    float f6 = act ? __uint_as_float(v.w << 16) : 0.f;
                    float f7 = act ? __uint_as_float(v.w & 0xFFFF0000u) : 0.f;
                    if (q == 0)      { sA[0]+=f0; sA[1]+=f1; sA[2]+=f2; sA[3]+=f3; sA[4]+=f4; sA[5]+=f5; sA[6]+=f6; sA[7]+=f7; }
                    else if (q == 1) { sB[0]+=f0; sB[1]+=f1; sB[2]+=f2; sB[3]+=f3; sB[4]+=f4; sB[5]+=f5; sB[6]+=f6; sB[7]+=f7; }
                    else if (q == 2) { sC[0]+=f0; sC[1]+=f1; sC[2]+=f2; sC[3]+=f3; sC[4]+=f4; sC[5]+=f5; sC[6]+=f6; sC[7]+=f7; }
                    else             { sD[0]+=f0; sD[1]+=f1; sD[2]+=f2; sD[3]+=f3; sD[4]+=f4; sD[5]+=f5; sD[6]+=f6; sD[7]+=f7; }
                }
            }
            if (nvalid) {
                float4 s;
                s.x = (sA[0] + sB[0]) + (sC[0] + sD[0]);
                s.y = (sA[1] + sB[1]) + (sC[1] + sD[1]);
                s.z = (sA[2] + sB[2]) + (sC[2] + sD[2]);
                s.w = (sA[3] + sB[3]) + (sC[3] + sD[3]);
                *(float4*)(agg + nd * 64 + dir * 32 + 8 * fp) = s;
                s.x = (sA[4] + sB[4]) + (sC[4] + sD[4]);
                s.y = (sA[5] + sB[5]) + (sC[5] + sD[5]);
                s.z = (sA[6] + sB[6]) + (sC[6] + sD[6]);
                s.w = (sA[7] + sB[7]) + (sC[7] + sD[7]);
                *(float4*)(agg + nd * 64 + dir * 32 + 8 * fp + 4) = s;
            }
        }
    }
}

// ==== thread-per-node dual-dir GIN MLP + BN stats (R10: scalar weights) =====

template <int DIN, bool BN_IN, bool IN_BF16>
__global__ __launch_bounds__(256, 2)
void dgin_mlp2(const void* __restrict__ xin_v, const float* __restrict__ agg,
               const int* __restrict__ off,
               const float* __restrict__ in_stats,
               const float* __restrict__ in_g, const float* __restrict__ in_b,
               const float* __restrict__ W1f, const float* __restrict__ b1f,
               const float* __restrict__ W2f, const float* __restrict__ b2f,
               const float* __restrict__ W1b, const float* __restrict__ b1b,
               const float* __restrict__ W2b, const float* __restrict__ b2b,
               unsigned short* __restrict__ out, float* __restrict__ stats, int n)
{
    const float* xf = (const float*)xin_v;
    const unsigned short* xb = (const unsigned short*)xin_v;

    __shared__ float sscale[32], sshift[32];
    __shared__ float sred[4 * 64];

    int tid = threadIdx.x;
    if (BN_IN && tid < 32) {
        float mu  = in_stats[tid] * INV_N;
        float var = in_stats[32 + tid] * INV_N - mu * mu;
        float sc  = in_g[tid] * rsqrtf(var + BN_EPS);
        sscale[tid] = sc;
        sshift[tid] = in_b[tid] - mu * sc;
    }
    if (BN_IN) __syncthreads();

    int n0 = blockIdx.x * 256 + tid;
    bool valid = (n0 < n);
    int node = valid ? n0 : (n - 1);

    // self row
    float xr[DIN];
    if (IN_BF16) {
        const uint4* xp = (const uint4*)(xb + node * 32);
        #pragma unroll
        for (int q = 0; q < 4; q++) {
            uint4 u = xp[q];
            unsigned int w[4] = {u.x, u.y, u.z, u.w};
            #pragma unroll
            for (int k = 0; k < 4; k++) {
                xr[8*q + 2*k]     = __uint_as_float(w[k] << 16);
                xr[8*q + 2*k + 1] = __uint_as_float(w[k] & 0xFFFF0000u);
            }
        }
    } else {
        const float2* xp = (const float2*)(xf + node * DIN);
        #pragma unroll
        for (int q = 0; q < DIN / 2; q++) {
            float2 w = xp[q];
            xr[2*q+0] = w.x; xr[2*q+1] = w.y;
        }
    }

    // both directions' aggregates upfront (R9 ILP hoist); fold into hv.
    float degp1A = (float)(off[node + 1] - off[node] + 1);
    float degp1B = (float)(off[N_NODES + node + 1] - off[N_NODES + node] + 1);

    float hvA[DIN], hvB[DIN];
    if (DIN == 32) {
        const float4* apA = (const float4*)(agg + node * 64);
        const float4* apB = (const float4*)(agg + node * 64 + 32);
        #pragma unroll
        for (int q = 0; q < 8; q++) {
            float4 a = apA[q];
            float4 b = apB[q];
            hvA[4*q+0] = xr[4*q+0] + a.x; hvA[4*q+1] = xr[4*q+1] + a.y;
            hvA[4*q+2] = xr[4*q+2] + a.z; hvA[4*q+3] = xr[4*q+3] + a.w;
            hvB[4*q+0] = xr[4*q+0] + b.x; hvB[4*q+1] = xr[4*q+1] + b.y;
            hvB[4*q+2] = xr[4*q+2] + b.z; hvB[4*q+3] = xr[4*q+3] + b.w;
        }
    } else {
        const float* apA = agg + node * (2 * DIN);
        const float* apB = apA + DIN;
        #pragma unroll
        for (int i = 0; i < DIN; i++) {
            hvA[i] = xr[i] + apA[i];
            hvB[i] = xr[i] + apB[i];
        }
    }
    if (BN_IN) {
        #pragma unroll
        for (int i = 0; i < DIN; i++) {
            hvA[i] = fmaf(sscale[i], hvA[i], degp1A * sshift[i]);
            hvB[i] = fmaf(sscale[i], hvB[i], degp1B * sshift[i]);
        }
    }

    float o[32];

    // ---------------- dir 0 (weights via uniform scalar loads) -------------
    {
        float t1[32];
        #pragma unroll
        for (int j = 0; j < 32; j++) t1[j] = b1f[j];
        #pragma unroll
        for (int i = 0; i < DIN; i++) {
            float hv = hvA[i];
            const float4* wr = (const float4*)(&W1f[i * 32]);
            #pragma unroll
            for (int q = 0; q < 8; q++) {
                float4 w = wr[q];
                t1[4*q+0] = fmaf(hv, w.x, t1[4*q+0]);
                t1[4*q+1] = fmaf(hv, w.y, t1[4*q+1]);
                t1[4*q+2] = fmaf(hv, w.z, t1[4*q+2]);
                t1[4*q+3] = fmaf(hv, w.w, t1[4*q+3]);
            }
        }
        #pragma unroll
        for (int j = 0; j < 32; j++) t1[j] = fmaxf(t1[j], 0.f);

        float o2[32];
        #pragma unroll
        for (int j = 0; j < 32; j++) o2[j] = b2f[j];
        #pragma unroll
        for (int i = 0; i < 32; i++) {
            float hv = t1[i];
            const float4* wr = (const float4*)(&W2f[i * 32]);
            #pragma unroll
            for (int q = 0; q < 8; q++) {
                float4 w = wr[q];
                o2[4*q+0] = fmaf(hv, w.x, o2[4*q+0]);
                o2[4*q+1] = fmaf(hv, w.y, o2[4*q+1]);
                o2[4*q+2] = fmaf(hv, w.z, o2[4*q+2]);
                o2[4*q+3] = fmaf(hv, w.w, o2[4*q+3]);
            }
        }
        #pragma unroll
        for (int j = 0; j < 32; j++) o[j] = fmaxf(o2[j], 0.f);
    }

    // ---------------- dir 1 ----------------
    {
        float t1[32];
        #pragma unroll
        for (int j = 0; j < 32; j++) t1[j] = b1b[j];
        #pragma unroll
        for (int i = 0; i < DIN; i++) {
            float hv = hvB[i];
            const float4* wr = (const float4*)(&W1b[i * 32]);
            #pragma unroll
            for (int q = 0; q < 8; q++) {
                float4 w = wr[q];
                t1[4*q+0] = fmaf(hv, w.x, t1[4*q+0]);
                t1[4*q+1] = fmaf(hv, w.y, t1[4*q+1]);
                t1[4*q+2] = fmaf(hv, w.z, t1[4*q+2]);
                t1[4*q+3] = fmaf(hv, w.w, t1[4*q+3]);
            }
        }
        #pragma unroll
        for (int j = 0; j < 32; j++) t1[j] = fmaxf(t1[j], 0.f);

        float o2[32];
        #pragma unroll
        for (int j = 0; j < 32; j++) o2[j] = b2b[j];
        #pragma unroll
        for (int i = 0; i < 32; i++) {
            float hv = t1[i];
            const float4* wr = (const float4*)(&W2b[i * 32]);
            #pragma unroll
            for (int q = 0; q < 8; q++) {
                float4 w = wr[q];
                o2[4*q+0] = fmaf(hv, w.x, o2[4*q+0]);
                o2[4*q+1] = fmaf(hv, w.y, o2[4*q+1]);
                o2[4*q+2] = fmaf(hv, w.z, o2[4*q+2]);
                o2[4*q+3] = fmaf(hv, w.w, o2[4*q+3]);
            }
        }
        #pragma unroll
        for (int j = 0; j < 32; j++) o[j] = 0.5f * (o[j] + fmaxf(o2[j], 0.f));
    }

    // round once to bf16; stats accumulate the ROUNDED value
    #pragma unroll
    for (int j = 0; j < 32; j++) o[j] = bf2f(f2bf(o[j]));

    if (valid) {
        uint4* op = (uint4*)(out + node * 32);
        #pragma unroll
        for (int q = 0; q < 4; q++) {
            uint4 u;
            u.x = (unsigned int)f2bf(o[8*q+0]) | ((unsigned int)f2bf(o[8*q+1]) << 16);
            u.y = (unsigned int)f2bf(o[8*q+2]) | ((unsigned int)f2bf(o[8*q+3]) << 16);
            u.z = (unsigned int)f2bf(o[8*q+4]) | ((unsigned int)f2bf(o[8*q+5]) << 16);
            u.w = (unsigned int)f2bf(o[8*q+6]) | ((unsigned int)f2bf(o[8*q+7]) << 16);
            op[q] = u;
        }
    }

    int lane = tid & 63;
    int wave = tid >> 6;
    #pragma unroll
    for (int f = 0; f < 32; f++) {
        float v = valid ? o[f] : 0.f;
        float v2 = v * v;
        #pragma unroll
        for (int offs = 32; offs > 0; offs >>= 1) {
            v  += __shfl_down(v, offs);
            v2 += __shfl_down(v2, offs);
        }
        if (lane == 0) {
            sred[wave * 64 + f]      = v;
            sred[wave * 64 + 32 + f] = v2;
        }
    }
    __syncthreads();
    if (tid < 64) {
        float a = sred[tid] + sred[64 + tid] + sred[128 + tid] + sred[192 + tid];
        atomicAdd(&stats[tid], a);
    }
}

// ================= segmented mean-pool (batch is sorted) + head =============

__global__ void pool_seg(const unsigned short* __restrict__ h, const int* __restrict__ batch,
                         float* __restrict__ psum, float* __restrict__ pcnt, int n)
{
    int tid = threadIdx.x;
    int grp = tid >> 5, f = tid & 31;
    int base = blockIdx.x * 256;
    float acc = 0.f, cnt = 0.f;
    int curg = -1;
    for (int it = 0; it < 32; it++) {
        int nd = base + grp + it * 8;
        if (nd < n) {
            int g = batch[nd];
            if (g != curg) {
                if (curg >= 0) {
                    atomicAdd(&psum[curg * 32 + f], acc);
                    if (f == 0) atomicAdd(&pcnt[curg], cnt);
                }
                curg = g; acc = 0.f; cnt = 0.f;
            }
            acc += bf2f(h[nd * 32 + f]);
            cnt += 1.f;
        }
    }
    if (curg >= 0) {
        atomicAdd(&psum[curg * 32 + f], acc);
        if (f == 0) atomicAdd(&pcnt[curg], cnt);
    }
}

__global__ void head_kernel(const float* __restrict__ psum, const float* __restrict__ pcnt,
                            const float* __restrict__ stats3,
                            const float* __restrict__ g3, const float* __restrict__ b3,
                            const float* __restrict__ lbW, const float* __restrict__ lbb,
                            const float* __restrict__ lmW, const float* __restrict__ lmb,
                            float* __restrict__ out)
{
    int g = threadIdx.x;  // 512 threads, one block
    float cnt = fmaxf(pcnt[g], 1.0f);
    float inv = 1.0f / cnt;
    float p[32];
    #pragma unroll
    for (int i = 0; i < 32; i++) {
        float mu  = stats3[i] * INV_N;
        float var = stats3[32 + i] * INV_N - mu * mu;
        float a   = g3[i] * rsqrtf(var + BN_EPS);
        float b   = b3[i] - mu * a;
        p[i] = fmaf(a, psum[g * 32 + i] * inv, b);
    }
    float z = lmb[0];
    #pragma unroll
    for (int k = 0; k < 16; k++) {
        float acc = lbb[k];
        #pragma unroll
        for (int i = 0; i < 32; i++) acc += p[i] * lbW[i * 16 + k];
        z += fmaxf(acc, 0.0f) * lmW[k];
    }
    out[g] = 1.0f / (1.0f + expf(-z));
}

// ================= launcher =================================================

extern "C" void kernel_launch(void* const* d_in, const int* in_sizes, int n_in,
                              void* d_out, int out_size, void* d_ws, size_t ws_size,
                              hipStream_t stream)
{
    const float* x   = (const float*)d_in[0];
    const int* ei    = (const int*)d_in[1];
    const int* batch = (const int*)d_in[2];
    const int* src = ei;
    const int* dst = ei + N_EDGES;
    char* ws = (char*)d_ws;

    auto W = [&](int l, int j) { return (const float*)d_in[3 + (l - 1) * 10 + j]; };

    // ---------------- layout ----------------
    unsigned short* h = (unsigned short*)(ws + 0);   // 16 MB (bf16 N x 32)
    float* xpad = (float*)(ws + 16000016);     // 8 MB (N x 8 fp32, padded x)
    float* agg  = (float*)(ws + 32000000);     // 64 MB (N x 64 fp32, F|B)
    int*   eidx = (int*)  (ws + 96000000);     // 20 MB
    int*   off  = (int*)  (ws + 116000000);    // (NT+1) ints
    // CSR-build temps inside the agg region (all dead before gather6p)
    int* gcnt  = (int*)(ws + 32000000);        // 512 ints
    int* bOffF = (int*)(ws + 32002048);        // NBUCK+1
    int* bOffB = (int*)(ws + 32003072);        // NBUCK+1
    int* cursF = (int*)(ws + 32004096);        // NBUCK
    int* cursB = (int*)(ws + 32005120);        // NBUCK
    unsigned int* payF = (unsigned int*)(ws + 32008192);  // 10 MB
    unsigned int* payB = (unsigned int*)(ws + 42008192);  // 10 MB
    float* stats1 = (float*)(ws + 118000016);
    float* stats2 = stats1 + 64;
    float* stats3 = stats1 + 128;
    float* psum   = (float*)(ws + 118000784);
    float* pcnt   = (float*)(ws + 118066320);

    // ---- CSR build v3: LDS bucket sort (no per-node device atomics)
    hipMemsetAsync(gcnt, 0, 2048, stream);
    k_histA<<<1024, 256, 0, stream>>>(src, dst, gcnt, N_EDGES);
    k_scanBk<<<1, 256, 0, stream>>>(gcnt, bOffF, bOffB, cursF, cursB, off);
    k_scatA<<<384, 256, 0, stream>>>(src, dst, cursF, cursB, payF, payB, N_EDGES);
    k_bucket<<<2 * NBUCK, 256, 0, stream>>>(payF, payB, bOffF, bOffB, eidx, off);

    pad_x<<<(N_NODES * 4 + 255) / 256, 256, 0, stream>>>(x, xpad, N_NODES);
    hipMemsetAsync(stats1, 0, 3 * 64 * 4, stream);

    const int GG   = 4096;
    const int NG64 = (N_NODES + 63) / 64;    // 3907 groups (packed layer-1)
    const int NG32 = (N_NODES + 31) / 32;    // 7813 groups (gather8x2)
    const int NG64g= (N_NODES + 63) / 64;    // 3907 groups (gather4x4)
    const int GM   = (N_NODES + 255) / 256;  // 977 mlp blocks (thread-per-node)

    // layer 1 (DIN=6): packed gather on xpad; mlp reads original fp32 x
    gather6p<<<GG, 256, 0, stream>>>(xpad, off, eidx, agg, NG64);
    dgin_mlp2<6, false, false><<<GM, 256, 0, stream>>>(
        x, agg, off, nullptr, nullptr, nullptr,
        W(1,0), W(1,1), W(1,2), W(1,3), W(1,4), W(1,5), W(1,6), W(1,7),
        h, stats1, N_NODES);

    // layer 2: uint2 gather (A of A/B)
    gather8x2<<<GG, 256, 0, stream>>>(h, off, eidx, agg, NG32);
    dgin_mlp2<32, true, true><<<GM, 256, 0, stream>>>(
        h, agg, off, stats1, W(1,8), W(1,9),
        W(2,0), W(2,1), W(2,2), W(2,3), W(2,4), W(2,5), W(2,6), W(2,7),
        h, stats2, N_NODES);

    // layer 3: uint4 gather (B of A/B)
    gather4x4<<<GG, 256, 0, stream>>>(h, off, eidx, agg, NG64g);
    dgin_mlp2<32, true, true><<<GM, 256, 0, stream>>>(
        h, agg, off, stats2, W(2,8), W(2,9),
        W(3,0), W(3,1), W(3,2), W(3,3), W(3,4), W(3,5), W(3,6), W(3,7),
        h, stats3, N_NODES);

    hipMemsetAsync(psum, 0, (size_t)N_GRAPHS * 32 * 4, stream);
    hipMemsetAsync(pcnt, 0, (size_t)N_GRAPHS * 4, stream);
    pool_seg<<<(N_NODES + 255) / 256, 256, 0, stream>>>(h, batch, psum, pcnt, N_NODES);
    head_kernel<<<1, 512, 0, stream>>>(psum, pcnt, stats3, W(3,8), W(3,9),
        (const float*)d_in[33], (const float*)d_in[34],
        (const float*)d_in[35], (const float*)d_in[36],
        (float*)d_out);
}

// Round 12
// 741.502 us; speedup vs baseline: 1.0680x; 1.0680x over previous
//
#include <hip/hip_runtime.h>
#include <math.h>

#define N_NODES 250000
#define N_EDGES 2500000
#define N_GRAPHS 512
#define BN_EPS 1e-5f
#define NT 500000   // 2*N_NODES offset slots (F then B)
#define INV_N (1.0f / (float)N_NODES)
#define NBUCK 245   // ceil(N_NODES / 1024)
#define BSHIFT 10

// bf16 helpers (RNE); bf16->fp32 is an exact bit shift.
__device__ __forceinline__ unsigned short f2bf(float x) {
    unsigned int u = __float_as_uint(x);
    unsigned int r = (u + 0x7FFFu + ((u >> 16) & 1u)) >> 16;
    return (unsigned short)r;
}
__device__ __forceinline__ float bf2f(unsigned short b) {
    return __uint_as_float(((unsigned int)b) << 16);
}

// ============== CSR build v3: two-level LDS bucket sort (R5 win) ============

__global__ __launch_bounds__(256)
void k_histA(const int* __restrict__ src, const int* __restrict__ dst,
             int* __restrict__ gcnt, int E)
{
    __shared__ int hF[256], hB[256];
    int t = threadIdx.x;
    hF[t] = 0; hB[t] = 0;
    __syncthreads();
    for (int e = blockIdx.x * 256 + t; e < E; e += gridDim.x * 256) {
        atomicAdd(&hF[dst[e] >> BSHIFT], 1);
        atomicAdd(&hB[src[e] >> BSHIFT], 1);
    }
    __syncthreads();
    if (hF[t]) atomicAdd(&gcnt[t], hF[t]);
    if (hB[t]) atomicAdd(&gcnt[256 + t], hB[t]);
}

__global__ void k_scanBk(const int* __restrict__ gcnt,
                         int* __restrict__ bOffF, int* __restrict__ bOffB,
                         int* __restrict__ cursF, int* __restrict__ cursB,
                         int* __restrict__ off)
{
    __shared__ int s[512];
    int t = threadIdx.x;   // 256
    int vF = (t < NBUCK) ? gcnt[t] : 0;
    int vB = (t < NBUCK) ? gcnt[256 + t] : 0;
    s[t] = vF; s[256 + t] = vB;
    __syncthreads();
    for (int o = 1; o < 256; o <<= 1) {
        int xF = (t >= o) ? s[t - o] : 0;
        int xB = (t >= o) ? s[256 + t - o] : 0;
        __syncthreads();
        s[t] += xF; s[256 + t] += xB;
        __syncthreads();
    }
    int exF = s[t] - vF;
    int exB = s[256 + t] - vB;
    if (t < NBUCK) {
        bOffF[t] = exF; cursF[t] = exF;
        bOffB[t] = exB; cursB[t] = exB;
    }
    if (t == 0) {
        bOffF[NBUCK] = N_EDGES;
        bOffB[NBUCK] = N_EDGES;
        off[NT] = 2 * N_EDGES;
    }
}

__global__ __launch_bounds__(256)
void k_scatA(const int* __restrict__ src, const int* __restrict__ dst,
             int* __restrict__ cursF, int* __restrict__ cursB,
             unsigned int* __restrict__ payF, unsigned int* __restrict__ payB, int E)
{
    __shared__ int hF[256], hB[256];
    __shared__ int cF[256], cB[256];
    int t = threadIdx.x;
    hF[t] = 0; hB[t] = 0;
    __syncthreads();
    int e0 = blockIdx.x * 256 + t, STR = gridDim.x * 256;
    for (int e = e0; e < E; e += STR) {
        atomicAdd(&hF[dst[e] >> BSHIFT], 1);
        atomicAdd(&hB[src[e] >> BSHIFT], 1);
    }
    __syncthreads();
    int baseF = 0, baseB = 0;
    if (t < NBUCK) {
        if (hF[t]) baseF = atomicAdd(&cursF[t], hF[t]);
        if (hB[t]) baseB = atomicAdd(&cursB[t], hB[t]);
    }
    __syncthreads();
    cF[t] = baseF; cB[t] = baseB;
    __syncthreads();
    for (int e = e0; e < E; e += STR) {
        int s = src[e], d = dst[e];
        int tf = atomicAdd(&cF[d >> BSHIFT], 1);
        payF[tf] = ((unsigned int)(d & 1023) << 18) | (unsigned int)s;
        int tb = atomicAdd(&cB[s >> BSHIFT], 1);
        payB[tb] = ((unsigned int)(s & 1023) << 18) | (unsigned int)d;
    }
}

__global__ __launch_bounds__(256)
void k_bucket(const unsigned int* __restrict__ payF, const unsigned int* __restrict__ payB,
              const int* __restrict__ bOffF, const int* __restrict__ bOffB,
              int* __restrict__ eidx, int* __restrict__ off)
{
    __shared__ int cnt[1024];
    __shared__ int ps[256];
    int blk = blockIdx.x;
    int d  = (blk >= NBUCK) ? 1 : 0;
    int bb = blk - d * NBUCK;
    const unsigned int* pay = d ? payB : payF;
    const int* bOff = d ? bOffB : bOffF;
    int t = threadIdx.x;
    int lo = bOff[bb], hi = bOff[bb + 1];

    #pragma unroll
    for (int k = 0; k < 4; k++) cnt[t + 256 * k] = 0;
    __syncthreads();
    for (int e = lo + t; e < hi; e += 256)
        atomicAdd(&cnt[pay[e] >> 18], 1);
    __syncthreads();

    int b4 = 4 * t;
    int v0 = cnt[b4], v1 = cnt[b4 + 1], v2 = cnt[b4 + 2], v3 = cnt[b4 + 3];
    int tsum = v0 + v1 + v2 + v3;
    ps[t] = tsum;
    __syncthreads();
    for (int o = 1; o < 256; o <<= 1) {
        int x = (t >= o) ? ps[t - o] : 0;
        __syncthreads();
        ps[t] += x;
        __syncthreads();
    }
    int run = ps[t] - tsum;
    int l0 = run, l1 = run + v0, l2 = run + v0 + v1, l3 = run + v0 + v1 + v2;
    cnt[b4] = l0; cnt[b4 + 1] = l1; cnt[b4 + 2] = l2; cnt[b4 + 3] = l3;

    int gbase = d * N_EDGES + lo;
    int node0 = bb * 1024 + b4;
    if (node0 + 0 < N_NODES) off[d * N_NODES + node0 + 0] = gbase + l0;
    if (node0 + 1 < N_NODES) off[d * N_NODES + node0 + 1] = gbase + l1;
    if (node0 + 2 < N_NODES) off[d * N_NODES + node0 + 2] = gbase + l2;
    if (node0 + 3 < N_NODES) off[d * N_NODES + node0 + 3] = gbase + l3;
    __syncthreads();

    for (int e = lo + t; e < hi; e += 256) {
        unsigned int p = pay[e];
        int r = atomicAdd(&cnt[p >> 18], 1);
        eidx[gbase + r] = (int)(p & 0x3FFFFu);
    }
}

// ================= pad x (N x 6 fp32) -> xpad (N x 8 fp32) ==================

__global__ void pad_x(const float* __restrict__ x, float* __restrict__ xpad, int n)
{
    int i = blockIdx.x * blockDim.x + threadIdx.x;   // one float2 out per thread
    if (i >= n * 4) return;
    int node = i >> 2, p2 = i & 3;
    float2 v;
    v.x = (2 * p2     < 6) ? x[node * 6 + 2 * p2]     : 0.f;
    v.y = (2 * p2 + 1 < 6) ? x[node * 6 + 2 * p2 + 1] : 0.f;
    *(float2*)(xpad + node * 8 + 2 * p2) = v;
}

// ============ layer-1 gather, PACKED: 4 lanes x float2 per padded row =======

__global__ __launch_bounds__(256, 8)
void gather6p(const float* __restrict__ xpad, const int* __restrict__ off,
              const int* __restrict__ eidx, float* __restrict__ agg, int ngroups)
{
    int tid = threadIdx.x;
    int p2   = tid & 3;       // float2 index within row (cols 2p2, 2p2+1)
    int slot = tid >> 2;      // 0..63 node slots per block
    for (int grp = blockIdx.x; grp < ngroups; grp += gridDim.x) {
        int node = grp * 64 + slot;
        bool nvalid = (node < N_NODES);
        int nd = nvalid ? node : 0;
        #pragma unroll
        for (int dir = 0; dir < 2; dir++) {
            int u = dir * N_NODES + nd;
            int k0 = off[u], k1 = off[u + 1];
            if (!nvalid) k1 = k0;
            float a0=0.f,a1=0.f,b0=0.f,b1=0.f,c0=0.f,c1=0.f,d0=0.f,d1=0.f;
            for (int p = k0; p < k1; p += 8) {
                #pragma unroll
                for (int q = 0; q < 8; q++) {
                    int kk = p + q;
                    bool act = (kk < k1);
                    int j = eidx[act ? kk : k0];
                    float2 v = *(const float2*)(xpad + j * 8 + 2 * p2);
                    float lo = act ? v.x : 0.f;
                    float hi = act ? v.y : 0.f;
                    if ((q & 3) == 0)      { a0 += lo; a1 += hi; }
                    else if ((q & 3) == 1) { b0 += lo; b1 += hi; }
                    else if ((q & 3) == 2) { c0 += lo; c1 += hi; }
                    else                   { d0 += lo; d1 += hi; }
                }
            }
            if (nvalid && p2 < 3) {
                float2 s;
                s.x = (a0 + b0) + (c0 + d0);
                s.y = (a1 + b1) + (c1 + d1);
                *(float2*)(agg + nd * 12 + dir * 6 + 2 * p2) = s;
            }
        }
    }
}

// ================= bf16 gather (DIN=32): ushort2 per lane, 16 lanes/row =====
// R10/R11 settled: 16 lanes/row (4 nodes/wave -> min degree-divergence) with
// 8-deep miss queue is the best gather variant; wide-load variants (8x2, 4x4)
// regressed (+50us) from max-degree divergence across more rows/wave, and
// 12-deep regressed vs 8-deep (91 vs ~85us).

__global__ __launch_bounds__(256, 8)
void gather16(const unsigned short* __restrict__ xb, const int* __restrict__ off,
              const int* __restrict__ eidx, float* __restrict__ agg, int ngroups)
{
    const unsigned int* xu = (const unsigned int*)xb;   // row = 16 uints
    int tid = threadIdx.x;
    int fp = tid & 15;
    int gg = tid >> 4;
    for (int grp = blockIdx.x; grp < ngroups; grp += gridDim.x) {
        int node = grp * 16 + gg;
        #pragma unroll
        for (int dir = 0; dir < 2; dir++) {
            int u = dir * N_NODES + node;
            int k0 = off[u], k1 = off[u + 1];
            float a0 = 0.f, a1 = 0.f, b0 = 0.f, b1 = 0.f;
            float c0 = 0.f, c1 = 0.f, d0 = 0.f, d1 = 0.f;
            for (int p = k0; p < k1; p += 8) {
                #pragma unroll
                for (int q = 0; q < 8; q++) {
                    int kk = p + q;
                    bool act = (kk < k1);
                    int j = eidx[act ? kk : k0];
                    unsigned int v = xu[j * 16 + fp];
                    float lo = act ? __uint_as_float(v << 16) : 0.f;
                    float hi = act ? __uint_as_float(v & 0xFFFF0000u) : 0.f;
                    if ((q & 3) == 0)      { a0 += lo; a1 += hi; }
                    else if ((q & 3) == 1) { b0 += lo; b1 += hi; }
                    else if ((q & 3) == 2) { c0 += lo; c1 += hi; }
                    else                   { d0 += lo; d1 += hi; }
                }
            }
            float2 s;
            s.x = (a0 + b0) + (c0 + d0);
            s.y = (a1 + b1) + (c1 + d1);
            *(float2*)(agg + node * 64 + dir * 32 + 2 * fp) = s;
        }
    }
}

// ==== thread-per-node dual-dir GIN MLP + BN stats (R10: scalar weights) =====

template <int DIN, bool BN_IN, bool IN_BF16>
__global__ __launch_bounds__(256, 2)
void dgin_mlp2(const void* __restrict__ xin_v, const float* __restrict__ agg,
               const int* __restrict__ off,
               const float* __restrict__ in_stats,
               const float* __restrict__ in_g, const float* __restrict__ in_b,
               const float* __restrict__ W1f, const float* __restrict__ b1f,
               const float* __restrict__ W2f, const float* __restrict__ b2f,
               const float* __restrict__ W1b, const float* __restrict__ b1b,
               const float* __restrict__ W2b, const float* __restrict__ b2b,
               unsigned short* __restrict__ out, float* __restrict__ stats, int n)
{
    const float* xf = (const float*)xin_v;
    const unsigned short* xb = (const unsigned short*)xin_v;

    __shared__ float sscale[32], sshift[32];
    __shared__ float sred[4 * 64];

    int tid = threadIdx.x;
    if (BN_IN && tid < 32) {
        float mu  = in_stats[tid] * INV_N;
        float var = in_stats[32 + tid] * INV_N - mu * mu;
        float sc  = in_g[tid] * rsqrtf(var + BN_EPS);
        sscale[tid] = sc;
        sshift[tid] = in_b[tid] - mu * sc;
    }
    if (BN_IN) __syncthreads();

    int n0 = blockIdx.x * 256 + tid;
    bool valid = (n0 < n);
    int node = valid ? n0 : (n - 1);

    // self row
    float xr[DIN];
    if (IN_BF16) {
        const uint4* xp = (const uint4*)(xb + node * 32);
        #pragma unroll
        for (int q = 0; q < 4; q++) {
            uint4 u = xp[q];
            unsigned int w[4] = {u.x, u.y, u.z, u.w};
            #pragma unroll
            for (int k = 0; k < 4; k++) {
                xr[8*q + 2*k]     = __uint_as_float(w[k] << 16);
                xr[8*q + 2*k + 1] = __uint_as_float(w[k] & 0xFFFF0000u);
            }
        }
    } else {
        const float2* xp = (const float2*)(xf + node * DIN);
        #pragma unroll
        for (int q = 0; q < DIN / 2; q++) {
            float2 w = xp[q];
            xr[2*q+0] = w.x; xr[2*q+1] = w.y;
        }
    }

    // both directions' aggregates upfront (R9 ILP hoist); fold into hv.
    float degp1A = (float)(off[node + 1] - off[node] + 1);
    float degp1B = (float)(off[N_NODES + node + 1] - off[N_NODES + node] + 1);

    float hvA[DIN], hvB[DIN];
    if (DIN == 32) {
        const float4* apA = (const float4*)(agg + node * 64);
        const float4* apB = (const float4*)(agg + node * 64 + 32);
        #pragma unroll
        for (int q = 0; q < 8; q++) {
            float4 a = apA[q];
            float4 b = apB[q];
            hvA[4*q+0] = xr[4*q+0] + a.x; hvA[4*q+1] = xr[4*q+1] + a.y;
            hvA[4*q+2] = xr[4*q+2] + a.z; hvA[4*q+3] = xr[4*q+3] + a.w;
            hvB[4*q+0] = xr[4*q+0] + b.x; hvB[4*q+1] = xr[4*q+1] + b.y;
            hvB[4*q+2] = xr[4*q+2] + b.z; hvB[4*q+3] = xr[4*q+3] + b.w;
        }
    } else {
        const float* apA = agg + node * (2 * DIN);
        const float* apB = apA + DIN;
        #pragma unroll
        for (int i = 0; i < DIN; i++) {
            hvA[i] = xr[i] + apA[i];
            hvB[i] = xr[i] + apB[i];
        }
    }
    if (BN_IN) {
        #pragma unroll
        for (int i = 0; i < DIN; i++) {
            hvA[i] = fmaf(sscale[i], hvA[i], degp1A * sshift[i]);
            hvB[i] = fmaf(sscale[i], hvB[i], degp1B * sshift[i]);
        }
    }

    float o[32];

    // ---------------- dir 0 (weights via uniform scalar loads) -------------
    {
        float t1[32];
        #pragma unroll
        for (int j = 0; j < 32; j++) t1[j] = b1f[j];
        #pragma unroll
        for (int i = 0; i < DIN; i++) {
            float hv = hvA[i];
            const float4* wr = (const float4*)(&W1f[i * 32]);
            #pragma unroll
            for (int q = 0; q < 8; q++) {
                float4 w = wr[q];
                t1[4*q+0] = fmaf(hv, w.x, t1[4*q+0]);
                t1[4*q+1] = fmaf(hv, w.y, t1[4*q+1]);
                t1[4*q+2] = fmaf(hv, w.z, t1[4*q+2]);
                t1[4*q+3] = fmaf(hv, w.w, t1[4*q+3]);
            }
        }
        #pragma unroll
        for (int j = 0; j < 32; j++) t1[j] = fmaxf(t1[j], 0.f);

        float o2[32];
        #pragma unroll
        for (int j = 0; j < 32; j++) o2[j] = b2f[j];
        #pragma unroll
        for (int i = 0; i < 32; i++) {
            float hv = t1[i];
            const float4* wr = (const float4*)(&W2f[i * 32]);
            #pragma unroll
            for (int q = 0; q < 8; q++) {
                float4 w = wr[q];
                o2[4*q+0] = fmaf(hv, w.x, o2[4*q+0]);
                o2[4*q+1] = fmaf(hv, w.y, o2[4*q+1]);
                o2[4*q+2] = fmaf(hv, w.z, o2[4*q+2]);
                o2[4*q+3] = fmaf(hv, w.w, o2[4*q+3]);
            }
        }
        #pragma unroll
        for (int j = 0; j < 32; j++) o[j] = fmaxf(o2[j], 0.f);
    }

    // ---------------- dir 1 ----------------
    {
        float t1[32];
        #pragma unroll
        for (int j = 0; j < 32; j++) t1[j] = b1b[j];
        #pragma unroll
        for (int i = 0; i < DIN; i++) {
            float hv = hvB[i];
            const float4* wr = (const float4*)(&W1b[i * 32]);
            #pragma unroll
            for (int q = 0; q < 8; q++) {
                float4 w = wr[q];
                t1[4*q+0] = fmaf(hv, w.x, t1[4*q+0]);
                t1[4*q+1] = fmaf(hv, w.y, t1[4*q+1]);
                t1[4*q+2] = fmaf(hv, w.z, t1[4*q+2]);
                t1[4*q+3] = fmaf(hv, w.w, t1[4*q+3]);
            }
        }
        #pragma unroll
        for (int j = 0; j < 32; j++) t1[j] = fmaxf(t1[j], 0.f);

        float o2[32];
        #pragma unroll
        for (int j = 0; j < 32; j++) o2[j] = b2b[j];
        #pragma unroll
        for (int i = 0; i < 32; i++) {
            float hv = t1[i];
            const float4* wr = (const float4*)(&W2b[i * 32]);
            #pragma unroll
            for (int q = 0; q < 8; q++) {
                float4 w = wr[q];
                o2[4*q+0] = fmaf(hv, w.x, o2[4*q+0]);
                o2[4*q+1] = fmaf(hv, w.y, o2[4*q+1]);
                o2[4*q+2] = fmaf(hv, w.z, o2[4*q+2]);
                o2[4*q+3] = fmaf(hv, w.w, o2[4*q+3]);
            }
        }
        #pragma unroll
        for (int j = 0; j < 32; j++) o[j] = 0.5f * (o[j] + fmaxf(o2[j], 0.f));
    }

    // round once to bf16; stats accumulate the ROUNDED value
    #pragma unroll
    for (int j = 0; j < 32; j++) o[j] = bf2f(f2bf(o[j]));

    if (valid) {
        uint4* op = (uint4*)(out + node * 32);
        #pragma unroll
        for (int q = 0; q < 4; q++) {
            uint4 u;
            u.x = (unsigned int)f2bf(o[8*q+0]) | ((unsigned int)f2bf(o[8*q+1]) << 16);
            u.y = (unsigned int)f2bf(o[8*q+2]) | ((unsigned int)f2bf(o[8*q+3]) << 16);
            u.z = (unsigned int)f2bf(o[8*q+4]) | ((unsigned int)f2bf(o[8*q+5]) << 16);
            u.w = (unsigned int)f2bf(o[8*q+6]) | ((unsigned int)f2bf(o[8*q+7]) << 16);
            op[q] = u;
        }
    }

    int lane = tid & 63;
    int wave = tid >> 6;
    #pragma unroll
    for (int f = 0; f < 32; f++) {
        float v = valid ? o[f] : 0.f;
        float v2 = v * v;
        #pragma unroll
        for (int offs = 32; offs > 0; offs >>= 1) {
            v  += __shfl_down(v, offs);
            v2 += __shfl_down(v2, offs);
        }
        if (lane == 0) {
            sred[wave * 64 + f]      = v;
            sred[wave * 64 + 32 + f] = v2;
        }
    }
    __syncthreads();
    if (tid < 64) {
        float a = sred[tid] + sred[64 + tid] + sred[128 + tid] + sred[192 + tid];
        atomicAdd(&stats[tid], a);
    }
}

// ================= segmented mean-pool (batch is sorted) + head =============

__global__ void pool_seg(const unsigned short* __restrict__ h, const int* __restrict__ batch,
                         float* __restrict__ psum, float* __restrict__ pcnt, int n)
{
    int tid = threadIdx.x;
    int grp = tid >> 5, f = tid & 31;
    int base = blockIdx.x * 256;
    float acc = 0.f, cnt = 0.f;
    int curg = -1;
    for (int it = 0; it < 32; it++) {
        int nd = base + grp + it * 8;
        if (nd < n) {
            int g = batch[nd];
            if (g != curg) {
                if (curg >= 0) {
                    atomicAdd(&psum[curg * 32 + f], acc);
                    if (f == 0) atomicAdd(&pcnt[curg], cnt);
                }
                curg = g; acc = 0.f; cnt = 0.f;
            }
            acc += bf2f(h[nd * 32 + f]);
            cnt += 1.f;
        }
    }
    if (curg >= 0) {
        atomicAdd(&psum[curg * 32 + f], acc);
        if (f == 0) atomicAdd(&pcnt[curg], cnt);
    }
}

__global__ void head_kernel(const float* __restrict__ psum, const float* __restrict__ pcnt,
                            const float* __restrict__ stats3,
                            const float* __restrict__ g3, const float* __restrict__ b3,
                            const float* __restrict__ lbW, const float* __restrict__ lbb,
                            const float* __restrict__ lmW, const float* __restrict__ lmb,
                            float* __restrict__ out)
{
    int g = threadIdx.x;  // 512 threads, one block
    float cnt = fmaxf(pcnt[g], 1.0f);
    float inv = 1.0f / cnt;
    float p[32];
    #pragma unroll
    for (int i = 0; i < 32; i++) {
        float mu  = stats3[i] * INV_N;
        float var = stats3[32 + i] * INV_N - mu * mu;
        float a   = g3[i] * rsqrtf(var + BN_EPS);
        float b   = b3[i] - mu * a;
        p[i] = fmaf(a, psum[g * 32 + i] * inv, b);
    }
    float z = lmb[0];
    #pragma unroll
    for (int k = 0; k < 16; k++) {
        float acc = lbb[k];
        #pragma unroll
        for (int i = 0; i < 32; i++) acc += p[i] * lbW[i * 16 + k];
        z += fmaxf(acc, 0.0f) * lmW[k];
    }
    out[g] = 1.0f / (1.0f + expf(-z));
}

// ================= launcher =================================================

extern "C" void kernel_launch(void* const* d_in, const int* in_sizes, int n_in,
                              void* d_out, int out_size, void* d_ws, size_t ws_size,
                              hipStream_t stream)
{
    const float* x   = (const float*)d_in[0];
    const int* ei    = (const int*)d_in[1];
    const int* batch = (const int*)d_in[2];
    const int* src = ei;
    const int* dst = ei + N_EDGES;
    char* ws = (char*)d_ws;

    auto W = [&](int l, int j) { return (const float*)d_in[3 + (l - 1) * 10 + j]; };

    // ---------------- layout ----------------
    unsigned short* h = (unsigned short*)(ws + 0);   // 16 MB (bf16 N x 32)
    float* xpad = (float*)(ws + 16000016);     // 8 MB (N x 8 fp32, padded x)
    float* agg  = (float*)(ws + 32000000);     // 64 MB (N x 64 fp32, F|B)
    int*   eidx = (int*)  (ws + 96000000);     // 20 MB
    int*   off  = (int*)  (ws + 116000000);    // (NT+1) ints
    // CSR-build temps inside the agg region (all dead before gather6p)
    int* gcnt  = (int*)(ws + 32000000);        // 512 ints
    int* bOffF = (int*)(ws + 32002048);        // NBUCK+1
    int* bOffB = (int*)(ws + 32003072);        // NBUCK+1
    int* cursF = (int*)(ws + 32004096);        // NBUCK
    int* cursB = (int*)(ws + 32005120);        // NBUCK
    unsigned int* payF = (unsigned int*)(ws + 32008192);  // 10 MB
    unsigned int* payB = (unsigned int*)(ws + 42008192);  // 10 MB
    float* stats1 = (float*)(ws + 118000016);
    float* stats2 = stats1 + 64;
    float* stats3 = stats1 + 128;
    float* psum   = (float*)(ws + 118000784);
    float* pcnt   = (float*)(ws + 118066320);

    // ---- CSR build v3: LDS bucket sort (no per-node device atomics)
    hipMemsetAsync(gcnt, 0, 2048, stream);
    k_histA<<<1024, 256, 0, stream>>>(src, dst, gcnt, N_EDGES);
    k_scanBk<<<1, 256, 0, stream>>>(gcnt, bOffF, bOffB, cursF, cursB, off);
    k_scatA<<<384, 256, 0, stream>>>(src, dst, cursF, cursB, payF, payB, N_EDGES);
    k_bucket<<<2 * NBUCK, 256, 0, stream>>>(payF, payB, bOffF, bOffB, eidx, off);

    pad_x<<<(N_NODES * 4 + 255) / 256, 256, 0, stream>>>(x, xpad, N_NODES);
    hipMemsetAsync(stats1, 0, 3 * 64 * 4, stream);

    const int GG   = 4096;
    const int NG64 = (N_NODES + 63) / 64;    // 3907 groups (packed layer-1)
    const int NG16 = N_NODES / 16;           // 15625 groups (bf16 gather16)
    const int GM   = (N_NODES + 255) / 256;  // 977 mlp blocks (thread-per-node)

    // layer 1 (DIN=6): packed gather on xpad; mlp reads original fp32 x
    gather6p<<<GG, 256, 0, stream>>>(xpad, off, eidx, agg, NG64);
    dgin_mlp2<6, false, false><<<GM, 256, 0, stream>>>(
        x, agg, off, nullptr, nullptr, nullptr,
        W(1,0), W(1,1), W(1,2), W(1,3), W(1,4), W(1,5), W(1,6), W(1,7),
        h, stats1, N_NODES);

    // layer 2: gather16 (8-deep, 16 lanes/row — proven best)
    gather16<<<GG, 256, 0, stream>>>(h, off, eidx, agg, NG16);
    dgin_mlp2<32, true, true><<<GM, 256, 0, stream>>>(
        h, agg, off, stats1, W(1,8), W(1,9),
        W(2,0), W(2,1), W(2,2), W(2,3), W(2,4), W(2,5), W(2,6), W(2,7),
        h, stats2, N_NODES);

    // layer 3: gather16 as well (R10 proved 8-deep > 12-deep)
    gather16<<<GG, 256, 0, stream>>>(h, off, eidx, agg, NG16);
    dgin_mlp2<32, true, true><<<GM, 256, 0, stream>>>(
        h, agg, off, stats2, W(2,8), W(2,9),
        W(3,0), W(3,1), W(3,2), W(3,3), W(3,4), W(3,5), W(3,6), W(3,7),
        h, stats3, N_NODES);

    hipMemsetAsync(psum, 0, (size_t)N_GRAPHS * 32 * 4, stream);
    hipMemsetAsync(pcnt, 0, (size_t)N_GRAPHS * 4, stream);
    pool_seg<<<(N_NODES + 255) / 256, 256, 0, stream>>>(h, batch, psum, pcnt, N_NODES);
    head_kernel<<<1, 512, 0, stream>>>(psum, pcnt, stats3, W(3,8), W(3,9),
        (const float*)d_in[33], (const float*)d_in[34],
        (const float*)d_in[35], (const float*)d_in[36],
        (float*)d_out);
}

// Round 13
// 733.914 us; speedup vs baseline: 1.0790x; 1.0103x over previous
//
#include <hip/hip_runtime.h>
#include <math.h>

#define N_NODES 250000
#define N_EDGES 2500000
#define N_GRAPHS 512
#define BN_EPS 1e-5f
#define NT 500000   // 2*N_NODES offset slots (F then B)
#define INV_N (1.0f / (float)N_NODES)
#define NBUCK 245   // ceil(N_NODES / 1024)
#define BSHIFT 10

// bf16 helpers (RNE); bf16->fp32 is an exact bit shift.
__device__ __forceinline__ unsigned short f2bf(float x) {
    unsigned int u = __float_as_uint(x);
    unsigned int r = (u + 0x7FFFu + ((u >> 16) & 1u)) >> 16;
    return (unsigned short)r;
}
__device__ __forceinline__ float bf2f(unsigned short b) {
    return __uint_as_float(((unsigned int)b) << 16);
}

// ============== CSR build v3: two-level LDS bucket sort (R5 win) ============

__global__ __launch_bounds__(256)
void k_histA(const int* __restrict__ src, const int* __restrict__ dst,
             int* __restrict__ gcnt, int E)
{
    __shared__ int hF[256], hB[256];
    int t = threadIdx.x;
    hF[t] = 0; hB[t] = 0;
    __syncthreads();
    for (int e = blockIdx.x * 256 + t; e < E; e += gridDim.x * 256) {
        atomicAdd(&hF[dst[e] >> BSHIFT], 1);
        atomicAdd(&hB[src[e] >> BSHIFT], 1);
    }
    __syncthreads();
    if (hF[t]) atomicAdd(&gcnt[t], hF[t]);
    if (hB[t]) atomicAdd(&gcnt[256 + t], hB[t]);
}

__global__ void k_scanBk(const int* __restrict__ gcnt,
                         int* __restrict__ bOffF, int* __restrict__ bOffB,
                         int* __restrict__ cursF, int* __restrict__ cursB,
                         int* __restrict__ off)
{
    __shared__ int s[512];
    int t = threadIdx.x;   // 256
    int vF = (t < NBUCK) ? gcnt[t] : 0;
    int vB = (t < NBUCK) ? gcnt[256 + t] : 0;
    s[t] = vF; s[256 + t] = vB;
    __syncthreads();
    for (int o = 1; o < 256; o <<= 1) {
        int xF = (t >= o) ? s[t - o] : 0;
        int xB = (t >= o) ? s[256 + t - o] : 0;
        __syncthreads();
        s[t] += xF; s[256 + t] += xB;
        __syncthreads();
    }
    int exF = s[t] - vF;
    int exB = s[256 + t] - vB;
    if (t < NBUCK) {
        bOffF[t] = exF; cursF[t] = exF;
        bOffB[t] = exB; cursB[t] = exB;
    }
    if (t == 0) {
        bOffF[NBUCK] = N_EDGES;
        bOffB[NBUCK] = N_EDGES;
        off[NT] = 2 * N_EDGES;
    }
}

__global__ __launch_bounds__(256)
void k_scatA(const int* __restrict__ src, const int* __restrict__ dst,
             int* __restrict__ cursF, int* __restrict__ cursB,
             unsigned int* __restrict__ payF, unsigned int* __restrict__ payB, int E)
{
    __shared__ int hF[256], hB[256];
    __shared__ int cF[256], cB[256];
    int t = threadIdx.x;
    hF[t] = 0; hB[t] = 0;
    __syncthreads();
    int e0 = blockIdx.x * 256 + t, STR = gridDim.x * 256;
    for (int e = e0; e < E; e += STR) {
        atomicAdd(&hF[dst[e] >> BSHIFT], 1);
        atomicAdd(&hB[src[e] >> BSHIFT], 1);
    }
    __syncthreads();
    int baseF = 0, baseB = 0;
    if (t < NBUCK) {
        if (hF[t]) baseF = atomicAdd(&cursF[t], hF[t]);
        if (hB[t]) baseB = atomicAdd(&cursB[t], hB[t]);
    }
    __syncthreads();
    cF[t] = baseF; cB[t] = baseB;
    __syncthreads();
    for (int e = e0; e < E; e += STR) {
        int s = src[e], d = dst[e];
        int tf = atomicAdd(&cF[d >> BSHIFT], 1);
        payF[tf] = ((unsigned int)(d & 1023) << 18) | (unsigned int)s;
        int tb = atomicAdd(&cB[s >> BSHIFT], 1);
        payB[tb] = ((unsigned int)(s & 1023) << 18) | (unsigned int)d;
    }
}

__global__ __launch_bounds__(256)
void k_bucket(const unsigned int* __restrict__ payF, const unsigned int* __restrict__ payB,
              const int* __restrict__ bOffF, const int* __restrict__ bOffB,
              int* __restrict__ eidx, int* __restrict__ off)
{
    __shared__ int cnt[1024];
    __shared__ int ps[256];
    int blk = blockIdx.x;
    int d  = (blk >= NBUCK) ? 1 : 0;
    int bb = blk - d * NBUCK;
    const unsigned int* pay = d ? payB : payF;
    const int* bOff = d ? bOffB : bOffF;
    int t = threadIdx.x;
    int lo = bOff[bb], hi = bOff[bb + 1];

    #pragma unroll
    for (int k = 0; k < 4; k++) cnt[t + 256 * k] = 0;
    __syncthreads();
    for (int e = lo + t; e < hi; e += 256)
        atomicAdd(&cnt[pay[e] >> 18], 1);
    __syncthreads();

    int b4 = 4 * t;
    int v0 = cnt[b4], v1 = cnt[b4 + 1], v2 = cnt[b4 + 2], v3 = cnt[b4 + 3];
    int tsum = v0 + v1 + v2 + v3;
    ps[t] = tsum;
    __syncthreads();
    for (int o = 1; o < 256; o <<= 1) {
        int x = (t >= o) ? ps[t - o] : 0;
        __syncthreads();
        ps[t] += x;
        __syncthreads();
    }
    int run = ps[t] - tsum;
    int l0 = run, l1 = run + v0, l2 = run + v0 + v1, l3 = run + v0 + v1 + v2;
    cnt[b4] = l0; cnt[b4 + 1] = l1; cnt[b4 + 2] = l2; cnt[b4 + 3] = l3;

    int gbase = d * N_EDGES + lo;
    int node0 = bb * 1024 + b4;
    if (node0 + 0 < N_NODES) off[d * N_NODES + node0 + 0] = gbase + l0;
    if (node0 + 1 < N_NODES) off[d * N_NODES + node0 + 1] = gbase + l1;
    if (node0 + 2 < N_NODES) off[d * N_NODES + node0 + 2] = gbase + l2;
    if (node0 + 3 < N_NODES) off[d * N_NODES + node0 + 3] = gbase + l3;
    __syncthreads();

    for (int e = lo + t; e < hi; e += 256) {
        unsigned int p = pay[e];
        int r = atomicAdd(&cnt[p >> 18], 1);
        eidx[gbase + r] = (int)(p & 0x3FFFFu);
    }
}

// ================= pad x (N x 6 fp32) -> xpad (N x 8 fp32) ==================

__global__ void pad_x(const float* __restrict__ x, float* __restrict__ xpad, int n)
{
    int i = blockIdx.x * blockDim.x + threadIdx.x;   // one float2 out per thread
    if (i >= n * 4) return;
    int node = i >> 2, p2 = i & 3;
    float2 v;
    v.x = (2 * p2     < 6) ? x[node * 6 + 2 * p2]     : 0.f;
    v.y = (2 * p2 + 1 < 6) ? x[node * 6 + 2 * p2 + 1] : 0.f;
    *(float2*)(xpad + node * 8 + 2 * p2) = v;
}

// ============ layer-1 gather, PACKED, tail-split (R13) ======================
// Bulk floor(deg/8) chunks run UNMASKED (no act cndmasks); one masked tail.
// Edge->slot mapping ((kk-k0)&3) and per-slot order unchanged -> bitwise-same.

__global__ __launch_bounds__(256, 8)
void gather6p(const float* __restrict__ xpad, const int* __restrict__ off,
              const int* __restrict__ eidx, float* __restrict__ agg, int ngroups)
{
    int tid = threadIdx.x;
    int p2   = tid & 3;       // float2 index within row (cols 2p2, 2p2+1)
    int slot = tid >> 2;      // 0..63 node slots per block
    for (int grp = blockIdx.x; grp < ngroups; grp += gridDim.x) {
        int node = grp * 64 + slot;
        bool nvalid = (node < N_NODES);
        int nd = nvalid ? node : 0;
        #pragma unroll
        for (int dir = 0; dir < 2; dir++) {
            int u = dir * N_NODES + nd;
            int k0 = off[u], k1 = off[u + 1];
            if (!nvalid) k1 = k0;
            float a0=0.f,a1=0.f,b0=0.f,b1=0.f,c0=0.f,c1=0.f,d0=0.f,d1=0.f;
            int pend = k0 + ((k1 - k0) & ~7);
            for (int p = k0; p < pend; p += 8) {
                #pragma unroll
                for (int q = 0; q < 8; q++) {
                    int j = eidx[p + q];
                    float2 v = *(const float2*)(xpad + j * 8 + 2 * p2);
                    if ((q & 3) == 0)      { a0 += v.x; a1 += v.y; }
                    else if ((q & 3) == 1) { b0 += v.x; b1 += v.y; }
                    else if ((q & 3) == 2) { c0 += v.x; c1 += v.y; }
                    else                   { d0 += v.x; d1 += v.y; }
                }
            }
            if (pend < k1) {
                #pragma unroll
                for (int q = 0; q < 8; q++) {
                    int kk = pend + q;
                    bool act = (kk < k1);
                    int j = eidx[act ? kk : k0];
                    float2 v = *(const float2*)(xpad + j * 8 + 2 * p2);
                    float lo = act ? v.x : 0.f;
                    float hi = act ? v.y : 0.f;
                    if ((q & 3) == 0)      { a0 += lo; a1 += hi; }
                    else if ((q & 3) == 1) { b0 += lo; b1 += hi; }
                    else if ((q & 3) == 2) { c0 += lo; c1 += hi; }
                    else                   { d0 += lo; d1 += hi; }
                }
            }
            if (nvalid && p2 < 3) {
                float2 s;
                s.x = (a0 + b0) + (c0 + d0);
                s.y = (a1 + b1) + (c1 + d1);
                *(float2*)(agg + nd * 12 + dir * 6 + 2 * p2) = s;
            }
        }
    }
}

// ====== bf16 gather (DIN=32), 16 lanes/row, tail-split (R13) ================
// R10-R12 settled: 16 lanes/row + 8-deep queue is the best variant. R13 strips
// the 3 cndmasks/edge from the bulk chunks (~35% VALU cut); FP order bitwise-
// identical (same edge->slot mapping, same per-slot order).

__global__ __launch_bounds__(256, 8)
void gather16(const unsigned short* __restrict__ xb, const int* __restrict__ off,
              const int* __restrict__ eidx, float* __restrict__ agg, int ngroups)
{
    const unsigned int* xu = (const unsigned int*)xb;   // row = 16 uints
    int tid = threadIdx.x;
    int fp = tid & 15;
    int gg = tid >> 4;
    for (int grp = blockIdx.x; grp < ngroups; grp += gridDim.x) {
        int node = grp * 16 + gg;
        #pragma unroll
        for (int dir = 0; dir < 2; dir++) {
            int u = dir * N_NODES + node;
            int k0 = off[u], k1 = off[u + 1];
            float a0 = 0.f, a1 = 0.f, b0 = 0.f, b1 = 0.f;
            float c0 = 0.f, c1 = 0.f, d0 = 0.f, d1 = 0.f;
            int pend = k0 + ((k1 - k0) & ~7);
            for (int p = k0; p < pend; p += 8) {
                #pragma unroll
                for (int q = 0; q < 8; q++) {
                    int j = eidx[p + q];
                    unsigned int v = xu[j * 16 + fp];
                    float lo = __uint_as_float(v << 16);
                    float hi = __uint_as_float(v & 0xFFFF0000u);
                    if ((q & 3) == 0)      { a0 += lo; a1 += hi; }
                    else if ((q & 3) == 1) { b0 += lo; b1 += hi; }
                    else if ((q & 3) == 2) { c0 += lo; c1 += hi; }
                    else                   { d0 += lo; d1 += hi; }
                }
            }
            if (pend < k1) {
                #pragma unroll
                for (int q = 0; q < 8; q++) {
                    int kk = pend + q;
                    bool act = (kk < k1);
                    int j = eidx[act ? kk : k0];
                    unsigned int v = xu[j * 16 + fp];
                    float lo = act ? __uint_as_float(v << 16) : 0.f;
                    float hi = act ? __uint_as_float(v & 0xFFFF0000u) : 0.f;
                    if ((q & 3) == 0)      { a0 += lo; a1 += hi; }
                    else if ((q & 3) == 1) { b0 += lo; b1 += hi; }
                    else if ((q & 3) == 2) { c0 += lo; c1 += hi; }
                    else                   { d0 += lo; d1 += hi; }
                }
            }
            float2 s;
            s.x = (a0 + b0) + (c0 + d0);
            s.y = (a1 + b1) + (c1 + d1);
            *(float2*)(agg + node * 64 + dir * 32 + 2 * fp) = s;
        }
    }
}

// ==== thread-per-node dual-dir GIN MLP + BN stats (R10: scalar weights) =====

template <int DIN, bool BN_IN, bool IN_BF16>
__global__ __launch_bounds__(256, 2)
void dgin_mlp2(const void* __restrict__ xin_v, const float* __restrict__ agg,
               const int* __restrict__ off,
               const float* __restrict__ in_stats,
               const float* __restrict__ in_g, const float* __restrict__ in_b,
               const float* __restrict__ W1f, const float* __restrict__ b1f,
               const float* __restrict__ W2f, const float* __restrict__ b2f,
               const float* __restrict__ W1b, const float* __restrict__ b1b,
               const float* __restrict__ W2b, const float* __restrict__ b2b,
               unsigned short* __restrict__ out, float* __restrict__ stats, int n)
{
    const float* xf = (const float*)xin_v;
    const unsigned short* xb = (const unsigned short*)xin_v;

    __shared__ float sscale[32], sshift[32];
    __shared__ float sred[4 * 64];

    int tid = threadIdx.x;
    if (BN_IN && tid < 32) {
        float mu  = in_stats[tid] * INV_N;
        float var = in_stats[32 + tid] * INV_N - mu * mu;
        float sc  = in_g[tid] * rsqrtf(var + BN_EPS);
        sscale[tid] = sc;
        sshift[tid] = in_b[tid] - mu * sc;
    }
    if (BN_IN) __syncthreads();

    int n0 = blockIdx.x * 256 + tid;
    bool valid = (n0 < n);
    int node = valid ? n0 : (n - 1);

    // self row
    float xr[DIN];
    if (IN_BF16) {
        const uint4* xp = (const uint4*)(xb + node * 32);
        #pragma unroll
        for (int q = 0; q < 4; q++) {
            uint4 u = xp[q];
            unsigned int w[4] = {u.x, u.y, u.z, u.w};
            #pragma unroll
            for (int k = 0; k < 4; k++) {
                xr[8*q + 2*k]     = __uint_as_float(w[k] << 16);
                xr[8*q + 2*k + 1] = __uint_as_float(w[k] & 0xFFFF0000u);
            }
        }
    } else {
        const float2* xp = (const float2*)(xf + node * DIN);
        #pragma unroll
        for (int q = 0; q < DIN / 2; q++) {
            float2 w = xp[q];
            xr[2*q+0] = w.x; xr[2*q+1] = w.y;
        }
    }

    // both directions' aggregates upfront (R9 ILP hoist); fold into hv.
    float degp1A = (float)(off[node + 1] - off[node] + 1);
    float degp1B = (float)(off[N_NODES + node + 1] - off[N_NODES + node] + 1);

    float hvA[DIN], hvB[DIN];
    if (DIN == 32) {
        const float4* apA = (const float4*)(agg + node * 64);
        const float4* apB = (const float4*)(agg + node * 64 + 32);
        #pragma unroll
        for (int q = 0; q < 8; q++) {
            float4 a = apA[q];
            float4 b = apB[q];
            hvA[4*q+0] = xr[4*q+0] + a.x; hvA[4*q+1] = xr[4*q+1] + a.y;
            hvA[4*q+2] = xr[4*q+2] + a.z; hvA[4*q+3] = xr[4*q+3] + a.w;
            hvB[4*q+0] = xr[4*q+0] + b.x; hvB[4*q+1] = xr[4*q+1] + b.y;
            hvB[4*q+2] = xr[4*q+2] + b.z; hvB[4*q+3] = xr[4*q+3] + b.w;
        }
    } else {
        const float* apA = agg + node * (2 * DIN);
        const float* apB = apA + DIN;
        #pragma unroll
        for (int i = 0; i < DIN; i++) {
            hvA[i] = xr[i] + apA[i];
            hvB[i] = xr[i] + apB[i];
        }
    }
    if (BN_IN) {
        #pragma unroll
        for (int i = 0; i < DIN; i++) {
            hvA[i] = fmaf(sscale[i], hvA[i], degp1A * sshift[i]);
            hvB[i] = fmaf(sscale[i], hvB[i], degp1B * sshift[i]);
        }
    }

    float o[32];

    // ---------------- dir 0 (weights via uniform scalar loads) -------------
    {
        float t1[32];
        #pragma unroll
        for (int j = 0; j < 32; j++) t1[j] = b1f[j];
        #pragma unroll
        for (int i = 0; i < DIN; i++) {
            float hv = hvA[i];
            const float4* wr = (const float4*)(&W1f[i * 32]);
            #pragma unroll
            for (int q = 0; q < 8; q++) {
                float4 w = wr[q];
                t1[4*q+0] = fmaf(hv, w.x, t1[4*q+0]);
                t1[4*q+1] = fmaf(hv, w.y, t1[4*q+1]);
                t1[4*q+2] = fmaf(hv, w.z, t1[4*q+2]);
                t1[4*q+3] = fmaf(hv, w.w, t1[4*q+3]);
            }
        }
        #pragma unroll
        for (int j = 0; j < 32; j++) t1[j] = fmaxf(t1[j], 0.f);

        float o2[32];
        #pragma unroll
        for (int j = 0; j < 32; j++) o2[j] = b2f[j];
        #pragma unroll
        for (int i = 0; i < 32; i++) {
            float hv = t1[i];
            const float4* wr = (const float4*)(&W2f[i * 32]);
            #pragma unroll
            for (int q = 0; q < 8; q++) {
                float4 w = wr[q];
                o2[4*q+0] = fmaf(hv, w.x, o2[4*q+0]);
                o2[4*q+1] = fmaf(hv, w.y, o2[4*q+1]);
                o2[4*q+2] = fmaf(hv, w.z, o2[4*q+2]);
                o2[4*q+3] = fmaf(hv, w.w, o2[4*q+3]);
            }
        }
        #pragma unroll
        for (int j = 0; j < 32; j++) o[j] = fmaxf(o2[j], 0.f);
    }

    // ---------------- dir 1 ----------------
    {
        float t1[32];
        #pragma unroll
        for (int j = 0; j < 32; j++) t1[j] = b1b[j];
        #pragma unroll
        for (int i = 0; i < DIN; i++) {
            float hv = hvB[i];
            const float4* wr = (const float4*)(&W1b[i * 32]);
            #pragma unroll
            for (int q = 0; q < 8; q++) {
                float4 w = wr[q];
                t1[4*q+0] = fmaf(hv, w.x, t1[4*q+0]);
                t1[4*q+1] = fmaf(hv, w.y, t1[4*q+1]);
                t1[4*q+2] = fmaf(hv, w.z, t1[4*q+2]);
                t1[4*q+3] = fmaf(hv, w.w, t1[4*q+3]);
            }
        }
        #pragma unroll
        for (int j = 0; j < 32; j++) t1[j] = fmaxf(t1[j], 0.f);

        float o2[32];
        #pragma unroll
        for (int j = 0; j < 32; j++) o2[j] = b2b[j];
        #pragma unroll
        for (int i = 0; i < 32; i++) {
            float hv = t1[i];
            const float4* wr = (const float4*)(&W2b[i * 32]);
            #pragma unroll
            for (int q = 0; q < 8; q++) {
                float4 w = wr[q];
                o2[4*q+0] = fmaf(hv, w.x, o2[4*q+0]);
                o2[4*q+1] = fmaf(hv, w.y, o2[4*q+1]);
                o2[4*q+2] = fmaf(hv, w.z, o2[4*q+2]);
                o2[4*q+3] = fmaf(hv, w.w, o2[4*q+3]);
            }
        }
        #pragma unroll
        for (int j = 0; j < 32; j++) o[j] = 0.5f * (o[j] + fmaxf(o2[j], 0.f));
    }

    // round once to bf16; stats accumulate the ROUNDED value
    #pragma unroll
    for (int j = 0; j < 32; j++) o[j] = bf2f(f2bf(o[j]));

    if (valid) {
        uint4* op = (uint4*)(out + node * 32);
        #pragma unroll
        for (int q = 0; q < 4; q++) {
            uint4 u;
            u.x = (unsigned int)f2bf(o[8*q+0]) | ((unsigned int)f2bf(o[8*q+1]) << 16);
            u.y = (unsigned int)f2bf(o[8*q+2]) | ((unsigned int)f2bf(o[8*q+3]) << 16);
            u.z = (unsigned int)f2bf(o[8*q+4]) | ((unsigned int)f2bf(o[8*q+5]) << 16);
            u.w = (unsigned int)f2bf(o[8*q+6]) | ((unsigned int)f2bf(o[8*q+7]) << 16);
            op[q] = u;
        }
    }

    int lane = tid & 63;
    int wave = tid >> 6;
    #pragma unroll
    for (int f = 0; f < 32; f++) {
        float v = valid ? o[f] : 0.f;
        float v2 = v * v;
        #pragma unroll
        for (int offs = 32; offs > 0; offs >>= 1) {
            v  += __shfl_down(v, offs);
            v2 += __shfl_down(v2, offs);
        }
        if (lane == 0) {
            sred[wave * 64 + f]      = v;
            sred[wave * 64 + 32 + f] = v2;
        }
    }
    __syncthreads();
    if (tid < 64) {
        float a = sred[tid] + sred[64 + tid] + sred[128 + tid] + sred[192 + tid];
        atomicAdd(&stats[tid], a);
    }
}

// ================= segmented mean-pool (batch is sorted) + head =============

__global__ void pool_seg(const unsigned short* __restrict__ h, const int* __restrict__ batch,
                         float* __restrict__ psum, float* __restrict__ pcnt, int n)
{
    int tid = threadIdx.x;
    int grp = tid >> 5, f = tid & 31;
    int base = blockIdx.x * 256;
    float acc = 0.f, cnt = 0.f;
    int curg = -1;
    for (int it = 0; it < 32; it++) {
        int nd = base + grp + it * 8;
        if (nd < n) {
            int g = batch[nd];
            if (g != curg) {
                if (curg >= 0) {
                    atomicAdd(&psum[curg * 32 + f], acc);
                    if (f == 0) atomicAdd(&pcnt[curg], cnt);
                }
                curg = g; acc = 0.f; cnt = 0.f;
            }
            acc += bf2f(h[nd * 32 + f]);
            cnt += 1.f;
        }
    }
    if (curg >= 0) {
        atomicAdd(&psum[curg * 32 + f], acc);
        if (f == 0) atomicAdd(&pcnt[curg], cnt);
    }
}

__global__ void head_kernel(const float* __restrict__ psum, const float* __restrict__ pcnt,
                            const float* __restrict__ stats3,
                            const float* __restrict__ g3, const float* __restrict__ b3,
                            const float* __restrict__ lbW, const float* __restrict__ lbb,
                            const float* __restrict__ lmW, const float* __restrict__ lmb,
                            float* __restrict__ out)
{
    int g = threadIdx.x;  // 512 threads, one block
    float cnt = fmaxf(pcnt[g], 1.0f);
    float inv = 1.0f / cnt;
    float p[32];
    #pragma unroll
    for (int i = 0; i < 32; i++) {
        float mu  = stats3[i] * INV_N;
        float var = stats3[32 + i] * INV_N - mu * mu;
        float a   = g3[i] * rsqrtf(var + BN_EPS);
        float b   = b3[i] - mu * a;
        p[i] = fmaf(a, psum[g * 32 + i] * inv, b);
    }
    float z = lmb[0];
    #pragma unroll
    for (int k = 0; k < 16; k++) {
        float acc = lbb[k];
        #pragma unroll
        for (int i = 0; i < 32; i++) acc += p[i] * lbW[i * 16 + k];
        z += fmaxf(acc, 0.0f) * lmW[k];
    }
    out[g] = 1.0f / (1.0f + expf(-z));
}

// ================= launcher =================================================

extern "C" void kernel_launch(void* const* d_in, const int* in_sizes, int n_in,
                              void* d_out, int out_size, void* d_ws, size_t ws_size,
                              hipStream_t stream)
{
    const float* x   = (const float*)d_in[0];
    const int* ei    = (const int*)d_in[1];
    const int* batch = (const int*)d_in[2];
    const int* src = ei;
    const int* dst = ei + N_EDGES;
    char* ws = (char*)d_ws;

    auto W = [&](int l, int j) { return (const float*)d_in[3 + (l - 1) * 10 + j]; };

    // ---------------- layout ----------------
    unsigned short* h = (unsigned short*)(ws + 0);   // 16 MB (bf16 N x 32)
    float* xpad = (float*)(ws + 16000016);     // 8 MB (N x 8 fp32, padded x)
    float* agg  = (float*)(ws + 32000000);     // 64 MB (N x 64 fp32, F|B)
    int*   eidx = (int*)  (ws + 96000000);     // 20 MB
    int*   off  = (int*)  (ws + 116000000);    // (NT+1) ints
    // CSR-build temps inside the agg region (all dead before gather6p)
    int* gcnt  = (int*)(ws + 32000000);        // 512 ints
    int* bOffF = (int*)(ws + 32002048);        // NBUCK+1
    int* bOffB = (int*)(ws + 32003072);        // NBUCK+1
    int* cursF = (int*)(ws + 32004096);        // NBUCK
    int* cursB = (int*)(ws + 32005120);        // NBUCK
    unsigned int* payF = (unsigned int*)(ws + 32008192);  // 10 MB
    unsigned int* payB = (unsigned int*)(ws + 42008192);  // 10 MB
    float* stats1 = (float*)(ws + 118000016);
    float* stats2 = stats1 + 64;
    float* stats3 = stats1 + 128;
    float* psum   = (float*)(ws + 118000784);
    float* pcnt   = (float*)(ws + 118066320);

    // ---- CSR build v3: LDS bucket sort (no per-node device atomics)
    hipMemsetAsync(gcnt, 0, 2048, stream);
    k_histA<<<1024, 256, 0, stream>>>(src, dst, gcnt, N_EDGES);
    k_scanBk<<<1, 256, 0, stream>>>(gcnt, bOffF, bOffB, cursF, cursB, off);
    k_scatA<<<384, 256, 0, stream>>>(src, dst, cursF, cursB, payF, payB, N_EDGES);
    k_bucket<<<2 * NBUCK, 256, 0, stream>>>(payF, payB, bOffF, bOffB, eidx, off);

    pad_x<<<(N_NODES * 4 + 255) / 256, 256, 0, stream>>>(x, xpad, N_NODES);
    hipMemsetAsync(stats1, 0, 3 * 64 * 4, stream);

    const int GG   = 4096;
    const int NG64 = (N_NODES + 63) / 64;    // 3907 groups (packed layer-1)
    const int NG16 = N_NODES / 16;           // 15625 groups (bf16 gather16)
    const int GM   = (N_NODES + 255) / 256;  // 977 mlp blocks (thread-per-node)

    // layer 1 (DIN=6): packed gather on xpad; mlp reads original fp32 x
    gather6p<<<GG, 256, 0, stream>>>(xpad, off, eidx, agg, NG64);
    dgin_mlp2<6, false, false><<<GM, 256, 0, stream>>>(
        x, agg, off, nullptr, nullptr, nullptr,
        W(1,0), W(1,1), W(1,2), W(1,3), W(1,4), W(1,5), W(1,6), W(1,7),
        h, stats1, N_NODES);

    // layer 2: gather16 (8-deep, 16 lanes/row, tail-split)
    gather16<<<GG, 256, 0, stream>>>(h, off, eidx, agg, NG16);
    dgin_mlp2<32, true, true><<<GM, 256, 0, stream>>>(
        h, agg, off, stats1, W(1,8), W(1,9),
        W(2,0), W(2,1), W(2,2), W(2,3), W(2,4), W(2,5), W(2,6), W(2,7),
        h, stats2, N_NODES);

    // layer 3: gather16 as well
    gather16<<<GG, 256, 0, stream>>>(h, off, eidx, agg, NG16);
    dgin_mlp2<32, true, true><<<GM, 256, 0, stream>>>(
        h, agg, off, stats2, W(2,8), W(2,9),
        W(3,0), W(3,1), W(3,2), W(3,3), W(3,4), W(3,5), W(3,6), W(3,7),
        h, stats3, N_NODES);

    hipMemsetAsync(psum, 0, (size_t)N_GRAPHS * 32 * 4, stream);
    hipMemsetAsync(pcnt, 0, (size_t)N_GRAPHS * 4, stream);
    pool_seg<<<(N_NODES + 255) / 256, 256, 0, stream>>>(h, batch, psum, pcnt, N_NODES);
    head_kernel<<<1, 512, 0, stream>>>(psum, pcnt, stats3, W(3,8), W(3,9),
        (const float*)d_in[33], (const float*)d_in[34],
        (const float*)d_in[35], (const float*)d_in[36],
        (float*)d_out);
}